// Round 3
// baseline (340.521 us; speedup 1.0000x reference)
//
#include <hip/hip_runtime.h>
#include <hip/hip_bf16.h>
#include <stdint.h>

typedef unsigned short u16;
typedef __bf16 bf16x8 __attribute__((ext_vector_type(8)));
typedef float f32x4 __attribute__((ext_vector_type(4)));

#define SEQ    2048
#define DMODEL 2048
#define NHEAD  16
#define DHEAD  128
// 1/sqrt(128) * log2(e): Q is pre-scaled so QK^T lands directly in exp2 domain
#define QSCALE (0.088388347648318447f * 1.4426950408889634f)

__device__ __forceinline__ u16 f2bf(float f){
  uint32_t u = __float_as_uint(f);
  u += 0x7FFFu + ((u >> 16) & 1u);        // round-to-nearest-even
  return (u16)(u >> 16);
}

__device__ __forceinline__ void gload_lds16(const u16* g, u16* l){
  __builtin_amdgcn_global_load_lds((const __attribute__((address_space(1))) void*)g,
                                   (__attribute__((address_space(3))) void*)l,
                                   16, 0, 0);
}

// ---------------- f32 -> bf16 conversion (vectorized) ----------------
__global__ __launch_bounds__(256) void cvt_bf16(const float* __restrict__ src,
                                                u16* __restrict__ dst, int n4){
  int i = blockIdx.x * 256 + threadIdx.x;
  if (i < n4){
    float4 v = reinterpret_cast<const float4*>(src)[i];
    ushort4 o;
    o.x = f2bf(v.x); o.y = f2bf(v.y); o.z = f2bf(v.z); o.w = f2bf(v.w);
    reinterpret_cast<ushort4*>(dst)[i] = o;
  }
}

// all 4 weight matrices in one launch; dst regions contiguous (4M u16 each)
__global__ __launch_bounds__(256) void cvt_w4(const float* __restrict__ Wq,
    const float* __restrict__ Wk, const float* __restrict__ Wv,
    const float* __restrict__ Wo, u16* __restrict__ dst){
  const int z = blockIdx.y;
  const float* s = (z==0) ? Wq : (z==1) ? Wk : (z==2) ? Wv : Wo;
  int i = blockIdx.x * 256 + threadIdx.x;
  float4 v = reinterpret_cast<const float4*>(s)[i];
  ushort4 o;
  o.x = f2bf(v.x); o.y = f2bf(v.y); o.z = f2bf(v.z); o.w = f2bf(v.w);
  reinterpret_cast<ushort4*>(dst + (size_t)z*4194304)[i] = o;
}

// ---------------- GEMM core: C = A(M,K) x W(N,K)^T ----------------
// 128x128 tile, BK=32, 4 waves (2x2 of 64x64), double-buffered LDS with
// 2-phase prefetch; chunk XOR key (row>>1)&3 -> 2-way bank aliasing (free).
__device__ __forceinline__ void gemm_stage(const u16* __restrict__ A,
    const u16* __restrict__ W, int bm, int bn, int k0,
    u16* ldsA, u16* ldsB, int wid, int lane){
  #pragma unroll
  for (int is = 0; is < 2; ++is){
    int o   = (wid*2 + is)*1024 + lane*16;    // byte offset in 8KB tile
    int row = o >> 6;                          // 64B per row (32 bf16)
    int sc  = ((o >> 4) & 3) ^ ((row >> 1) & 3);
    gload_lds16(A + (size_t)(bm + row)*DMODEL + k0 + sc*8, ldsA + (wid*2+is)*512);
    gload_lds16(W + (size_t)(bn + row)*DMODEL + k0 + sc*8, ldsB + (wid*2+is)*512);
  }
}

__device__ __forceinline__ void gemm_compute(const u16* ldsA, const u16* ldsB,
    f32x4 acc[4][4], int wr, int wc, int g, int ln){
  bf16x8 a[4], b[4];
  #pragma unroll
  for (int m = 0; m < 4; ++m){
    int row = wr*64 + m*16 + ln;
    int ch  = g ^ ((row >> 1) & 3);
    a[m] = *reinterpret_cast<const bf16x8*>(ldsA + row*32 + ch*8);
  }
  #pragma unroll
  for (int n = 0; n < 4; ++n){
    int row = wc*64 + n*16 + ln;
    int ch  = g ^ ((row >> 1) & 3);
    b[n] = *reinterpret_cast<const bf16x8*>(ldsB + row*32 + ch*8);
  }
  #pragma unroll
  for (int m = 0; m < 4; ++m)
    #pragma unroll
    for (int n = 0; n < 4; ++n)
      acc[m][n] = __builtin_amdgcn_mfma_f32_16x16x32_bf16(a[m], b[n], acc[m][n], 0, 0, 0);
}

__device__ __forceinline__ void gemm_core(const u16* __restrict__ A,
                                          const u16* __restrict__ W,
                                          int bm, int bn,
                                          u16 (*ldsA)[128*32], u16 (*ldsB)[128*32],
                                          f32x4 acc[4][4]){
  const int tid  = threadIdx.x;
  const int wid  = tid >> 6, lane = tid & 63;
  const int g    = lane >> 4, ln = lane & 15;
  const int wr   = wid >> 1, wc = wid & 1;
  const f32x4 z4 = {0.f, 0.f, 0.f, 0.f};
  #pragma unroll
  for (int m = 0; m < 4; ++m)
    #pragma unroll
    for (int n = 0; n < 4; ++n) acc[m][n] = z4;

  // prologue: stage tile 0, drain, barrier
  gemm_stage(A, W, bm, bn, 0, ldsA[0], ldsB[0], wid, lane);
  asm volatile("s_waitcnt vmcnt(0)" ::: "memory");
  __builtin_amdgcn_s_barrier();

  int cur = 0;
  for (int k0 = 0; k0 < DMODEL; k0 += 32){
    if (k0 + 32 < DMODEL)
      gemm_stage(A, W, bm, bn, k0 + 32, ldsA[cur^1], ldsB[cur^1], wid, lane);
    gemm_compute(ldsA[cur], ldsB[cur], acc, wr, wc, g, ln);
    asm volatile("s_waitcnt vmcnt(0) lgkmcnt(0)" ::: "memory");
    __builtin_amdgcn_s_barrier();
    cur ^= 1;
  }
}

// QKV projection: z=0 -> Q (bf16, pre-scaled by QSCALE), z=1 -> K,
// z=2 -> V stored transposed as (B*H, DHEAD, SEQ).
__global__ __launch_bounds__(256) void gemm_qkv(const u16* __restrict__ A,
    const u16* __restrict__ Wq, const u16* __restrict__ Wk, const u16* __restrict__ Wv,
    u16* __restrict__ Q, u16* __restrict__ K, u16* __restrict__ Vt){
  __shared__ __align__(16) u16 ldsA[2][128*32];
  __shared__ __align__(16) u16 ldsB[2][128*32];
  const int z = blockIdx.z;
  const u16* W = (z == 0) ? Wq : (z == 1) ? Wk : Wv;
  const int bm = blockIdx.x * 128, bn = blockIdx.y * 128;
  f32x4 acc[4][4];
  gemm_core(A, W, bm, bn, ldsA, ldsB, acc);
  const int tid = threadIdx.x;
  const int wid = tid >> 6, lane = tid & 63;
  const int g = lane >> 4, ln = lane & 15;
  const int wr = wid >> 1, wc = wid & 1;
  if (z < 2){
    u16* C = (z == 0) ? Q : K;
    const float sc = (z == 0) ? QSCALE : 1.0f;
    #pragma unroll
    for (int m = 0; m < 4; ++m)
      #pragma unroll
      for (int n = 0; n < 4; ++n){
        int col = bn + wc*64 + n*16 + ln;
        #pragma unroll
        for (int i = 0; i < 4; ++i){
          int row = bm + wr*64 + m*16 + g*4 + i;
          C[(size_t)row*DMODEL + col] = f2bf(acc[m][n][i] * sc);
        }
      }
  } else {
    #pragma unroll
    for (int m = 0; m < 4; ++m)
      #pragma unroll
      for (int n = 0; n < 4; ++n){
        int col  = bn + wc*64 + n*16 + ln;
        int row0 = bm + wr*64 + m*16 + g*4;
        int bb   = row0 >> 11, lt = row0 & (SEQ-1);
        ushort4 pk;
        pk.x = f2bf(acc[m][n][0]); pk.y = f2bf(acc[m][n][1]);
        pk.z = f2bf(acc[m][n][2]); pk.w = f2bf(acc[m][n][3]);
        *reinterpret_cast<ushort4*>(Vt + (size_t)(bb*DMODEL + col)*SEQ + lt) = pk;
      }
  }
}

// Output projection: fp32 epilogue straight to d_out.
__global__ __launch_bounds__(256) void gemm_out(const u16* __restrict__ A,
    const u16* __restrict__ Wo, float* __restrict__ C){
  __shared__ __align__(16) u16 ldsA[2][128*32];
  __shared__ __align__(16) u16 ldsB[2][128*32];
  const int bm = blockIdx.x * 128, bn = blockIdx.y * 128;
  f32x4 acc[4][4];
  gemm_core(A, Wo, bm, bn, ldsA, ldsB, acc);
  const int tid = threadIdx.x;
  const int wid = tid >> 6, lane = tid & 63;
  const int g = lane >> 4, ln = lane & 15;
  const int wr = wid >> 1, wc = wid & 1;
  #pragma unroll
  for (int m = 0; m < 4; ++m)
    #pragma unroll
    for (int n = 0; n < 4; ++n){
      int col = bn + wc*64 + n*16 + ln;
      #pragma unroll
      for (int i = 0; i < 4; ++i){
        int row = bm + wr*64 + m*16 + g*4 + i;
        C[(size_t)row*DMODEL + col] = acc[m][n][i];
      }
    }
}

// ---------------- causal flash attention v2 (unchanged from round 2) ------
__device__ __forceinline__ void attn_stage(const u16* __restrict__ Kb,
    const u16* __restrict__ Vtb, u16* Kd, u16* Vd,
    int b, int bh, int h, int t, int w, int lane){
  #pragma unroll
  for (int is = 0; is < 4; ++is){
    int o = w*4096 + is*1024 + lane*16;
    int rowK = o >> 8;                         // K rows: 256B each
    int scK  = ((o >> 4) & 15) ^ (rowK & 7);
    gload_lds16(Kb + (size_t)(b*SEQ + t*64 + rowK)*DMODEL + h*DHEAD + scK*8,
                Kd + w*2048 + is*512);
    int rowV = o >> 7;                         // V^T rows: 128B each
    int scV  = ((o >> 4) & 7) ^ (rowV & 7);
    gload_lds16(Vtb + (size_t)(bh*DHEAD + rowV)*SEQ + t*64 + scV*8,
                Vd + w*2048 + is*512);
  }
}

template<bool MASKED>
__device__ __forceinline__ void attn_tile(const u16* Kc, const u16* Vc, u16* pw,
                                          const bf16x8 qf[4], f32x4 yacc[8],
                                          float& mrun, float& lrun,
                                          int w, int lane){
  const int g = lane >> 4, ln = lane & 15;
  f32x4 st[4];
  __builtin_amdgcn_s_setprio(1);
  #pragma unroll
  for (int kt = 0; kt < 4; ++kt){
    f32x4 accs = {0.f,0.f,0.f,0.f};
    #pragma unroll
    for (int c = 0; c < 4; ++c){
      int row = kt*16 + ln;
      int ch  = (c*4 + g) ^ (row & 7);
      bf16x8 kf = *reinterpret_cast<const bf16x8*>(Kc + row*128 + ch*8);
      accs = __builtin_amdgcn_mfma_f32_16x16x32_bf16(kf, qf[c], accs, 0, 0, 0);
    }
    st[kt] = accs;
  }
  __builtin_amdgcn_s_setprio(0);

  float p[16];
  float tmax = -1e30f;
  #pragma unroll
  for (int kt = 0; kt < 4; ++kt)
    #pragma unroll
    for (int i = 0; i < 4; ++i){
      float s = st[kt][i];
      if (MASKED && (kt*16 + g*4 + i) > (w*16 + ln)) s = -1e30f;
      p[kt*4+i] = s;
      tmax = fmaxf(tmax, s);
    }
  tmax = fmaxf(tmax, __shfl_xor(tmax, 16));
  tmax = fmaxf(tmax, __shfl_xor(tmax, 32));

  if (!__all(tmax - mrun <= 11.5f)){
    float mn = fmaxf(mrun, tmax);
    float fr = __builtin_amdgcn_exp2f(mrun - mn);
    lrun *= fr;
    float fi[4];
    #pragma unroll
    for (int i = 0; i < 4; ++i) fi[i] = __shfl(fr, g*4 + i);
    #pragma unroll
    for (int dt = 0; dt < 8; ++dt)
      #pragma unroll
      for (int i = 0; i < 4; ++i) yacc[dt][i] *= fi[i];
    mrun = mn;
  }
  float psum = 0.f;
  #pragma unroll
  for (int j = 0; j < 16; ++j){
    p[j] = __builtin_amdgcn_exp2f(p[j] - mrun);
    psum += p[j];
  }
  psum += __shfl_xor(psum, 16);
  psum += __shfl_xor(psum, 32);
  lrun += psum;

  #pragma unroll
  for (int kt = 0; kt < 4; ++kt)
    #pragma unroll
    for (int pr = 0; pr < 2; ++pr){
      uint32_t pk = (uint32_t)f2bf(p[kt*4 + 2*pr]) |
                    ((uint32_t)f2bf(p[kt*4 + 2*pr + 1]) << 16);
      int byte = (kt*16 + g*4 + 2*pr)*2;
      int ch   = (byte >> 4) ^ (ln & 7);
      int addr = ln*128 + (ch << 4) + (byte & 15);
      *reinterpret_cast<uint32_t*>(reinterpret_cast<char*>(pw) + addr) = pk;
    }

  __builtin_amdgcn_s_setprio(1);
  #pragma unroll
  for (int kc = 0; kc < 2; ++kc){
    int chp = (kc*4 + g) ^ (ln & 7);
    bf16x8 pf = *reinterpret_cast<const bf16x8*>(pw + ln*64 + chp*8);
    #pragma unroll
    for (int dt = 0; dt < 8; ++dt){
      int row = dt*16 + ln;
      int chv = (kc*4 + g) ^ (row & 7);
      bf16x8 vf = *reinterpret_cast<const bf16x8*>(Vc + row*64 + chv*8);
      yacc[dt] = __builtin_amdgcn_mfma_f32_16x16x32_bf16(pf, vf, yacc[dt], 0, 0, 0);
    }
  }
  __builtin_amdgcn_s_setprio(0);
}

__global__ __launch_bounds__(256) void attn_fwd(const u16* __restrict__ Qb,
    const u16* __restrict__ Kb, const u16* __restrict__ Vtb, u16* __restrict__ Yb){
  __shared__ __align__(16) u16 Kt[2][64*128];
  __shared__ __align__(16) u16 Vt[2][128*64];
  __shared__ __align__(16) u16 Pl[4][16*64];
  const int tid = threadIdx.x, w = tid >> 6, lane = tid & 63;
  const int g = lane >> 4, ln = lane & 15;
  const int qt = (SEQ/64 - 1) - blockIdx.x;     // LPT: long blocks first
  const int bh = blockIdx.y;
  const int b = bh >> 4, h = bh & 15;
  const int qw = qt*64 + w*16;

  bf16x8 qf[4];
  {
    const u16* qp = Qb + (size_t)(b*SEQ + qw + ln)*DMODEL + h*DHEAD + g*8;
    #pragma unroll
    for (int c = 0; c < 4; ++c) qf[c] = *reinterpret_cast<const bf16x8*>(qp + c*32);
  }
  float mrun = -1e30f, lrun = 0.f;
  f32x4 yacc[8];
  {
    const f32x4 z4 = {0.f,0.f,0.f,0.f};
    #pragma unroll
    for (int dt = 0; dt < 8; ++dt) yacc[dt] = z4;
  }

  attn_stage(Kb, Vtb, &Kt[0][0], &Vt[0][0], b, bh, h, 0, w, lane);
  asm volatile("s_waitcnt vmcnt(0)" ::: "memory");
  __builtin_amdgcn_s_barrier();

  int cur = 0;
  for (int t = 0; t < qt; ++t){
    attn_stage(Kb, Vtb, &Kt[cur^1][0], &Vt[cur^1][0], b, bh, h, t+1, w, lane);
    attn_tile<false>(&Kt[cur][0], &Vt[cur][0], &Pl[w][0], qf, yacc, mrun, lrun, w, lane);
    asm volatile("s_waitcnt vmcnt(0) lgkmcnt(0)" ::: "memory");
    __builtin_amdgcn_s_barrier();
    cur ^= 1;
  }
  attn_tile<true>(&Kt[cur][0], &Vt[cur][0], &Pl[w][0], qf, yacc, mrun, lrun, w, lane);

  float inv[4];
  #pragma unroll
  for (int i = 0; i < 4; ++i){
    float li = __shfl(lrun, g*4 + i);
    inv[i] = __builtin_amdgcn_rcpf(li);
  }
  #pragma unroll
  for (int dt = 0; dt < 8; ++dt)
    #pragma unroll
    for (int i = 0; i < 4; ++i){
      Yb[(size_t)(b*SEQ + qw + g*4 + i)*DMODEL + h*DHEAD + dt*16 + ln] =
          f2bf(yacc[dt][i] * inv[i]);
    }
}

// ---------------- launcher ----------------
extern "C" void kernel_launch(void* const* d_in, const int* in_sizes, int n_in,
                              void* d_out, int out_size, void* d_ws, size_t ws_size,
                              hipStream_t stream) {
  const float* x  = (const float*)d_in[0];
  const float* Wq = (const float*)d_in[1];
  const float* Wk = (const float*)d_in[2];
  const float* Wv = (const float*)d_in[3];
  const float* Wo = (const float*)d_in[4];
  float* out = (float*)d_out;

  char* ws = (char*)d_ws;
  u16* xb  = (u16*)(ws +          0);
  u16* Wqb = (u16*)(ws + 16777216);    // Wq/Wk/Wv/Wo contiguous (32MB)
  u16* Wkb = (u16*)(ws + 25165824);
  u16* Wvb = (u16*)(ws + 33554432);
  u16* Wob = (u16*)(ws + 41943040);
  u16* Qb  = (u16*)(ws + 50331648);
  u16* Kb  = (u16*)(ws + 67108864);
  u16* Vtb = (u16*)(ws + 83886080);
  u16* Yb  = (u16*)(ws + 100663296);

  cvt_bf16<<<dim3(8192), 256, 0, stream>>>(x, xb, 2097152);
  cvt_w4<<<dim3(4096, 4), 256, 0, stream>>>(Wq, Wk, Wv, Wo, Wqb);

  gemm_qkv<<<dim3(32, 16, 3), 256, 0, stream>>>(xb, Wqb, Wkb, Wvb, Qb, Kb, Vtb);

  attn_fwd<<<dim3(32, 32), 256, 0, stream>>>(Qb, Kb, Vtb, Yb);

  gemm_out<<<dim3(32, 16), 256, 0, stream>>>(Yb, Wob, out);
}

// Round 4
// 334.780 us; speedup vs baseline: 1.0171x; 1.0171x over previous
//
#include <hip/hip_runtime.h>
#include <hip/hip_bf16.h>
#include <stdint.h>

typedef unsigned short u16;
typedef __bf16 bf16x8 __attribute__((ext_vector_type(8)));
typedef float f32x4 __attribute__((ext_vector_type(4)));

#define SEQ    2048
#define DMODEL 2048
#define NHEAD  16
#define DHEAD  128
// 1/sqrt(128) * log2(e): Q pre-scaled so QK^T lands directly in exp2 domain
#define QSCALE (0.088388347648318447f * 1.4426950408889634f)

__device__ __forceinline__ u16 f2bf(float f){
  uint32_t u = __float_as_uint(f);
  u += 0x7FFFu + ((u >> 16) & 1u);        // round-to-nearest-even
  return (u16)(u >> 16);
}

__device__ __forceinline__ void gload_lds16(const u16* g, u16* l){
  __builtin_amdgcn_global_load_lds((const __attribute__((address_space(1))) void*)g,
                                   (__attribute__((address_space(3))) void*)l,
                                   16, 0, 0);
}

// ---------------- f32 -> bf16 conversion ----------------
__global__ __launch_bounds__(256) void cvt_bf16(const float* __restrict__ src,
                                                u16* __restrict__ dst, int n4){
  int i = blockIdx.x * 256 + threadIdx.x;
  if (i < n4){
    float4 v = reinterpret_cast<const float4*>(src)[i];
    ushort4 o;
    o.x = f2bf(v.x); o.y = f2bf(v.y); o.z = f2bf(v.z); o.w = f2bf(v.w);
    reinterpret_cast<ushort4*>(dst)[i] = o;
  }
}

__global__ __launch_bounds__(256) void cvt_w4(const float* __restrict__ Wq,
    const float* __restrict__ Wk, const float* __restrict__ Wv,
    const float* __restrict__ Wo, u16* __restrict__ dst){
  const int z = blockIdx.y;
  const float* s = (z==0) ? Wq : (z==1) ? Wk : (z==2) ? Wv : Wo;
  int i = blockIdx.x * 256 + threadIdx.x;
  float4 v = reinterpret_cast<const float4*>(s)[i];
  ushort4 o;
  o.x = f2bf(v.x); o.y = f2bf(v.y); o.z = f2bf(v.z); o.w = f2bf(v.w);
  reinterpret_cast<ushort4*>(dst + (size_t)z*4194304)[i] = o;
}

// ============ 256x256 8-phase GEMM core: C = A(M,K) x W(N,K)^T ============
// BK=64, 512 threads (8 waves as 2Mx4N), per-wave 128x64 output (acc[8][4]).
// LDS [2buf][256 rows][64 bf16] for A and B (128 KiB), row-XOR swizzle
// chunk ^= row&7 (G4 fix; involution applied on stage-source and ds_read).
// 4 phases/K-tile, Gray (0,0),(0,1),(1,1),(1,0); 1 half-tile stage/phase;
// counted vmcnt(4) once per K-tile (vmcnt(0) only in the last 2 tiles).

// half-tile stagers: 16KB region, 2 x global_load_lds per thread.
// A half mh: rows {mh*64..+64} u {128+mh*64..+64}  (read by quadrant mh)
__device__ __forceinline__ void stageA(const u16* __restrict__ G, int grow0, int kt,
                                       int half, u16* lds, int w, int lane){
  #pragma unroll
  for (int j = 0; j < 2; ++j){
    int q   = w*2 + j;                                   // 0..15
    int r0  = ((q & 8) << 4) + half*64 + (q & 7)*8;      // 8-row group start
    int row = r0 + (lane >> 3);
    int sc  = (lane & 7) ^ (row & 7);                    // inverse swizzle
    gload_lds16(G + (size_t)(grow0 + row)*DMODEL + kt*64 + sc*8, lds + r0*64);
  }
}
// B half nh: rows where (row>>5)&1 == nh (four 32-row stripes)
__device__ __forceinline__ void stageB(const u16* __restrict__ G, int grow0, int kt,
                                       int half, u16* lds, int w, int lane){
  #pragma unroll
  for (int j = 0; j < 2; ++j){
    int q   = w*2 + j;
    int r0  = ((q >> 2) << 6) + half*32 + (q & 3)*8;
    int row = r0 + (lane >> 3);
    int sc  = (lane & 7) ^ (row & 7);
    gload_lds16(G + (size_t)(grow0 + row)*DMODEL + kt*64 + sc*8, lds + r0*64);
  }
}

__device__ __forceinline__ bf16x8 ldsf(const u16* lds, int row, int c){
  return *reinterpret_cast<const bf16x8*>(lds + row*64 + (((c ^ (row & 7)) & 7) << 3));
}

template<int MH>
__device__ __forceinline__ void load_a(bf16x8 (&a)[4][2], const u16* LA,
                                       int wr, int ln, int g){
  #pragma unroll
  for (int m = 0; m < 4; ++m){
    int row = wr*128 + MH*64 + m*16 + ln;
    a[m][0] = ldsf(LA, row, g);
    a[m][1] = ldsf(LA, row, 4 + g);
  }
}
template<int NH>
__device__ __forceinline__ void load_b(bf16x8 (&b)[2][2], const u16* LB,
                                       int wc, int ln, int g){
  #pragma unroll
  for (int n = 0; n < 2; ++n){
    int row = wc*64 + NH*32 + n*16 + ln;
    b[n][0] = ldsf(LB, row, g);
    b[n][1] = ldsf(LB, row, 4 + g);
  }
}

template<int MH, int NH>
__device__ __forceinline__ void mfma_quad(f32x4 (&acc)[8][4], bf16x8 (&a)[4][2],
                                          bf16x8 (&b)[2][2]){
  __builtin_amdgcn_s_setprio(1);
  #pragma unroll
  for (int m = 0; m < 4; ++m)
    #pragma unroll
    for (int n = 0; n < 2; ++n){
      acc[MH*4+m][NH*2+n] = __builtin_amdgcn_mfma_f32_16x16x32_bf16(
          a[m][0], b[n][0], acc[MH*4+m][NH*2+n], 0, 0, 0);
      acc[MH*4+m][NH*2+n] = __builtin_amdgcn_mfma_f32_16x16x32_bf16(
          a[m][1], b[n][1], acc[MH*4+m][NH*2+n], 0, 0, 0);
    }
  __builtin_amdgcn_s_setprio(0);
}

__device__ __forceinline__ void phase_pre(){
  __builtin_amdgcn_s_barrier();
  asm volatile("s_waitcnt lgkmcnt(0)" ::: "memory");
  __builtin_amdgcn_sched_barrier(0);
}

__device__ __forceinline__ void gemm8_core(const u16* __restrict__ A,
    const u16* __restrict__ W, int bm, int bnl,
    u16 (*ldsA)[256*64], u16 (*ldsB)[256*64], f32x4 (&acc)[8][4],
    int w, int lane, int wr, int wc, int g, int ln){
  const f32x4 z4 = {0.f,0.f,0.f,0.f};
  #pragma unroll
  for (int i = 0; i < 8; ++i)
    #pragma unroll
    for (int j = 0; j < 4; ++j) acc[i][j] = z4;

  // prologue: tile0 all 4 halves + tile1 {A-h0, B-h1}; wait all but last 2
  stageA(A, bm, 0, 0, ldsA[0], w, lane);
  stageB(W, bnl, 0, 1, ldsB[0], w, lane);
  stageA(A, bm, 0, 1, ldsA[0], w, lane);
  stageB(W, bnl, 0, 0, ldsB[0], w, lane);
  stageA(A, bm, 1, 0, ldsA[1], w, lane);
  stageB(W, bnl, 1, 1, ldsB[1], w, lane);
  asm volatile("s_waitcnt vmcnt(4)" ::: "memory");
  __builtin_amdgcn_s_barrier();

  bf16x8 a[4][2], b[2][2];
  const int NT = DMODEL/64;   // 32
  for (int t = 0; t < NT; ++t){
    const int cur = t & 1;
    const u16* LA = ldsA[cur];
    const u16* LB = ldsB[cur];
    // phase 0: quad(0,0); stage A-h1 of tile t+1 (other buffer)
    load_a<0>(a, LA, wr, ln, g);
    load_b<0>(b, LB, wc, ln, g);
    if (t+1 < NT) stageA(A, bm, t+1, 1, ldsA[cur^1], w, lane);
    phase_pre();
    mfma_quad<0,0>(acc, a, b);
    __builtin_amdgcn_s_barrier();
    // phase 1: quad(0,1); stage B-h0 of tile t+1
    load_b<1>(b, LB, wc, ln, g);
    if (t+1 < NT) stageB(W, bnl, t+1, 0, ldsB[cur^1], w, lane);
    phase_pre();
    mfma_quad<0,1>(acc, a, b);
    __builtin_amdgcn_s_barrier();
    // phase 2: quad(1,1); stage A-h0 of tile t+2 (this buffer; region done)
    load_a<1>(a, LA, wr, ln, g);
    if (t+2 < NT) stageA(A, bm, t+2, 0, ldsA[cur], w, lane);
    phase_pre();
    mfma_quad<1,1>(acc, a, b);
    __builtin_amdgcn_s_barrier();
    // phase 3: quad(1,0); stage B-h1 of tile t+2; per-tile counted vmcnt
    load_b<0>(b, LB, wc, ln, g);
    if (t+2 < NT) stageB(W, bnl, t+2, 1, ldsB[cur], w, lane);
    if (t < NT-2) { asm volatile("s_waitcnt vmcnt(4)" ::: "memory"); }
    else          { asm volatile("s_waitcnt vmcnt(0)" ::: "memory"); }
    phase_pre();
    mfma_quad<1,0>(acc, a, b);
    __builtin_amdgcn_s_barrier();
  }
}

// Fused QKV: grid 384 blocks; n-tile 0..23 -> z = nt>>3 (Q/K/V), 8 n-tiles each.
__global__ __launch_bounds__(512, 2) void gemm_qkv8(const u16* __restrict__ A,
    const u16* __restrict__ Wall, u16* __restrict__ Q, u16* __restrict__ Kb,
    u16* __restrict__ Vt){
  __shared__ __align__(16) u16 ldsA[2][256*64];
  __shared__ __align__(16) u16 ldsB[2][256*64];
  const int tid = threadIdx.x, w = tid >> 6, lane = tid & 63;
  const int g = lane >> 4, ln = lane & 15;
  const int wr = w >> 2, wc = w & 3;
  const int bid = blockIdx.x;
  const int swz = (bid & 7)*48 + (bid >> 3);      // XCD-bijective (384 = 8*48)
  const int nt = swz >> 4, mt = swz & 15;         // W-panel reuse within XCD
  const int bm = mt*256, z = nt >> 3, bnl = (nt & 7) << 8;
  const u16* W = Wall + ((size_t)z << 22);
  f32x4 acc[8][4];
  gemm8_core(A, W, bm, bnl, ldsA, ldsB, acc, w, lane, wr, wc, g, ln);

  if (z < 2){
    u16* C = (z == 0) ? Q : Kb;
    const float sc = (z == 0) ? QSCALE : 1.0f;
    #pragma unroll
    for (int mf = 0; mf < 8; ++mf)
      #pragma unroll
      for (int nf = 0; nf < 4; ++nf){
        int col = bnl + wc*64 + nf*16 + ln;
        #pragma unroll
        for (int i = 0; i < 4; ++i){
          int row = bm + wr*128 + mf*16 + g*4 + i;
          C[(size_t)row*DMODEL + col] = f2bf(acc[mf][nf][i] * sc);
        }
      }
  } else {
    #pragma unroll
    for (int mf = 0; mf < 8; ++mf)
      #pragma unroll
      for (int nf = 0; nf < 4; ++nf){
        int col  = bnl + wc*64 + nf*16 + ln;     // h*128 + d
        int row0 = bm + wr*128 + mf*16 + g*4;    // 4 consecutive tokens
        int bb   = row0 >> 11, lt = row0 & (SEQ-1);
        ushort4 pk;
        pk.x = f2bf(acc[mf][nf][0]); pk.y = f2bf(acc[mf][nf][1]);
        pk.z = f2bf(acc[mf][nf][2]); pk.w = f2bf(acc[mf][nf][3]);
        *reinterpret_cast<ushort4*>(Vt + (size_t)(bb*DMODEL + col)*SEQ + lt) = pk;
      }
  }
}

// Output projection: fp32 epilogue straight to d_out. grid 128 blocks.
__global__ __launch_bounds__(512, 2) void gemm_out8(const u16* __restrict__ A,
    const u16* __restrict__ Wo, float* __restrict__ C){
  __shared__ __align__(16) u16 ldsA[2][256*64];
  __shared__ __align__(16) u16 ldsB[2][256*64];
  const int tid = threadIdx.x, w = tid >> 6, lane = tid & 63;
  const int g = lane >> 4, ln = lane & 15;
  const int wr = w >> 2, wc = w & 3;
  const int bid = blockIdx.x;
  const int swz = (bid & 7)*16 + (bid >> 3);      // 128 = 8*16
  const int nt = swz >> 4, mt = swz & 15;
  const int bm = mt*256, bnl = nt << 8;
  f32x4 acc[8][4];
  gemm8_core(A, Wo, bm, bnl, ldsA, ldsB, acc, w, lane, wr, wc, g, ln);
  #pragma unroll
  for (int mf = 0; mf < 8; ++mf)
    #pragma unroll
    for (int nf = 0; nf < 4; ++nf){
      int col = bnl + wc*64 + nf*16 + ln;
      #pragma unroll
      for (int i = 0; i < 4; ++i){
        int row = bm + wr*128 + mf*16 + g*4 + i;
        C[(size_t)row*DMODEL + col] = acc[mf][nf][i];
      }
    }
}

// ---------------- causal flash attention (unchanged from round 2) ----------
__device__ __forceinline__ void attn_stage(const u16* __restrict__ Kb,
    const u16* __restrict__ Vtb, u16* Kd, u16* Vd,
    int b, int bh, int h, int t, int w, int lane){
  #pragma unroll
  for (int is = 0; is < 4; ++is){
    int o = w*4096 + is*1024 + lane*16;
    int rowK = o >> 8;                         // K rows: 256B each
    int scK  = ((o >> 4) & 15) ^ (rowK & 7);
    gload_lds16(Kb + (size_t)(b*SEQ + t*64 + rowK)*DMODEL + h*DHEAD + scK*8,
                Kd + w*2048 + is*512);
    int rowV = o >> 7;                         // V^T rows: 128B each
    int scV  = ((o >> 4) & 7) ^ (rowV & 7);
    gload_lds16(Vtb + (size_t)(bh*DHEAD + rowV)*SEQ + t*64 + scV*8,
                Vd + w*2048 + is*512);
  }
}

template<bool MASKED>
__device__ __forceinline__ void attn_tile(const u16* Kc, const u16* Vc, u16* pw,
                                          const bf16x8 qf[4], f32x4 yacc[8],
                                          float& mrun, float& lrun,
                                          int w, int lane){
  const int g = lane >> 4, ln = lane & 15;
  f32x4 st[4];
  __builtin_amdgcn_s_setprio(1);
  #pragma unroll
  for (int kt = 0; kt < 4; ++kt){
    f32x4 accs = {0.f,0.f,0.f,0.f};
    #pragma unroll
    for (int c = 0; c < 4; ++c){
      int row = kt*16 + ln;
      int ch  = (c*4 + g) ^ (row & 7);
      bf16x8 kf = *reinterpret_cast<const bf16x8*>(Kc + row*128 + ch*8);
      accs = __builtin_amdgcn_mfma_f32_16x16x32_bf16(kf, qf[c], accs, 0, 0, 0);
    }
    st[kt] = accs;
  }
  __builtin_amdgcn_s_setprio(0);

  float p[16];
  float tmax = -1e30f;
  #pragma unroll
  for (int kt = 0; kt < 4; ++kt)
    #pragma unroll
    for (int i = 0; i < 4; ++i){
      float s = st[kt][i];
      if (MASKED && (kt*16 + g*4 + i) > (w*16 + ln)) s = -1e30f;
      p[kt*4+i] = s;
      tmax = fmaxf(tmax, s);
    }
  tmax = fmaxf(tmax, __shfl_xor(tmax, 16));
  tmax = fmaxf(tmax, __shfl_xor(tmax, 32));

  if (!__all(tmax - mrun <= 11.5f)){
    float mn = fmaxf(mrun, tmax);
    float fr = __builtin_amdgcn_exp2f(mrun - mn);
    lrun *= fr;
    float fi[4];
    #pragma unroll
    for (int i = 0; i < 4; ++i) fi[i] = __shfl(fr, g*4 + i);
    #pragma unroll
    for (int dt = 0; dt < 8; ++dt)
      #pragma unroll
      for (int i = 0; i < 4; ++i) yacc[dt][i] *= fi[i];
    mrun = mn;
  }
  float psum = 0.f;
  #pragma unroll
  for (int j = 0; j < 16; ++j){
    p[j] = __builtin_amdgcn_exp2f(p[j] - mrun);
    psum += p[j];
  }
  psum += __shfl_xor(psum, 16);
  psum += __shfl_xor(psum, 32);
  lrun += psum;

  #pragma unroll
  for (int kt = 0; kt < 4; ++kt)
    #pragma unroll
    for (int pr = 0; pr < 2; ++pr){
      uint32_t pk = (uint32_t)f2bf(p[kt*4 + 2*pr]) |
                    ((uint32_t)f2bf(p[kt*4 + 2*pr + 1]) << 16);
      int byte = (kt*16 + g*4 + 2*pr)*2;
      int ch   = (byte >> 4) ^ (ln & 7);
      int addr = ln*128 + (ch << 4) + (byte & 15);
      *reinterpret_cast<uint32_t*>(reinterpret_cast<char*>(pw) + addr) = pk;
    }

  __builtin_amdgcn_s_setprio(1);
  #pragma unroll
  for (int kc = 0; kc < 2; ++kc){
    int chp = (kc*4 + g) ^ (ln & 7);
    bf16x8 pf = *reinterpret_cast<const bf16x8*>(pw + ln*64 + chp*8);
    #pragma unroll
    for (int dt = 0; dt < 8; ++dt){
      int row = dt*16 + ln;
      int chv = (kc*4 + g) ^ (row & 7);
      bf16x8 vf = *reinterpret_cast<const bf16x8*>(Vc + row*64 + chv*8);
      yacc[dt] = __builtin_amdgcn_mfma_f32_16x16x32_bf16(pf, vf, yacc[dt], 0, 0, 0);
    }
  }
  __builtin_amdgcn_s_setprio(0);
}

__global__ __launch_bounds__(256) void attn_fwd(const u16* __restrict__ Qb,
    const u16* __restrict__ Kb, const u16* __restrict__ Vtb, u16* __restrict__ Yb){
  __shared__ __align__(16) u16 Kt[2][64*128];
  __shared__ __align__(16) u16 Vt[2][128*64];
  __shared__ __align__(16) u16 Pl[4][16*64];
  const int tid = threadIdx.x, w = tid >> 6, lane = tid & 63;
  const int g = lane >> 4, ln = lane & 15;
  const int qt = (SEQ/64 - 1) - blockIdx.x;     // LPT: long blocks first
  const int bh = blockIdx.y;
  const int b = bh >> 4, h = bh & 15;
  const int qw = qt*64 + w*16;

  bf16x8 qf[4];
  {
    const u16* qp = Qb + (size_t)(b*SEQ + qw + ln)*DMODEL + h*DHEAD + g*8;
    #pragma unroll
    for (int c = 0; c < 4; ++c) qf[c] = *reinterpret_cast<const bf16x8*>(qp + c*32);
  }
  float mrun = -1e30f, lrun = 0.f;
  f32x4 yacc[8];
  {
    const f32x4 z4 = {0.f,0.f,0.f,0.f};
    #pragma unroll
    for (int dt = 0; dt < 8; ++dt) yacc[dt] = z4;
  }

  attn_stage(Kb, Vtb, &Kt[0][0], &Vt[0][0], b, bh, h, 0, w, lane);
  asm volatile("s_waitcnt vmcnt(0)" ::: "memory");
  __builtin_amdgcn_s_barrier();

  int cur = 0;
  for (int t = 0; t < qt; ++t){
    attn_stage(Kb, Vtb, &Kt[cur^1][0], &Vt[cur^1][0], b, bh, h, t+1, w, lane);
    attn_tile<false>(&Kt[cur][0], &Vt[cur][0], &Pl[w][0], qf, yacc, mrun, lrun, w, lane);
    asm volatile("s_waitcnt vmcnt(0) lgkmcnt(0)" ::: "memory");
    __builtin_amdgcn_s_barrier();
    cur ^= 1;
  }
  attn_tile<true>(&Kt[cur][0], &Vt[cur][0], &Pl[w][0], qf, yacc, mrun, lrun, w, lane);

  float inv[4];
  #pragma unroll
  for (int i = 0; i < 4; ++i){
    float li = __shfl(lrun, g*4 + i);
    inv[i] = __builtin_amdgcn_rcpf(li);
  }
  #pragma unroll
  for (int dt = 0; dt < 8; ++dt)
    #pragma unroll
    for (int i = 0; i < 4; ++i){
      Yb[(size_t)(b*SEQ + qw + g*4 + i)*DMODEL + h*DHEAD + dt*16 + ln] =
          f2bf(yacc[dt][i] * inv[i]);
    }
}

// ---------------- launcher ----------------
extern "C" void kernel_launch(void* const* d_in, const int* in_sizes, int n_in,
                              void* d_out, int out_size, void* d_ws, size_t ws_size,
                              hipStream_t stream) {
  const float* x  = (const float*)d_in[0];
  const float* Wq = (const float*)d_in[1];
  const float* Wk = (const float*)d_in[2];
  const float* Wv = (const float*)d_in[3];
  const float* Wo = (const float*)d_in[4];
  float* out = (float*)d_out;

  char* ws = (char*)d_ws;
  u16* xb  = (u16*)(ws +          0);
  u16* Wqb = (u16*)(ws + 16777216);    // Wq/Wk/Wv/Wo contiguous (32MB)
  u16* Wob = (u16*)(ws + 41943040);
  u16* Qb  = (u16*)(ws + 50331648);
  u16* Kb  = (u16*)(ws + 67108864);
  u16* Vtb = (u16*)(ws + 83886080);
  u16* Yb  = (u16*)(ws + 100663296);

  cvt_bf16<<<dim3(8192), 256, 0, stream>>>(x, xb, 2097152);
  cvt_w4<<<dim3(4096, 4), 256, 0, stream>>>(Wq, Wk, Wv, Wo, Wqb);

  gemm_qkv8<<<dim3(384), 512, 0, stream>>>(xb, Wqb, Qb, Kb, Vtb);

  attn_fwd<<<dim3(32, 32), 256, 0, stream>>>(Qb, Kb, Vtb, Yb);

  gemm_out8<<<dim3(128), 512, 0, stream>>>(Yb, Wob, out);
}